// Round 9
// baseline (11953.487 us; speedup 1.0000x reference)
//
#include <hip/hip_runtime.h>

// Problem constants (fixed by reference setup)
#define B_ 32
#define T_ 8192
#define I_ 16
#define H_ 128
#define P_ 1024
#define O_ 3
#define BBW 168   // bb row stride in f16 (336 B: 16B-aligned; conflict-spread)

typedef _Float16 f16x4 __attribute__((ext_vector_type(4)));
typedef _Float16 frag  __attribute__((ext_vector_type(8)));   // MFMA A/B operand
typedef float    fragf __attribute__((ext_vector_type(4)));   // MFMA C/D

#define MFMA16(d, a, b) d = __builtin_amdgcn_mfma_f32_16x16x32_f16((a), (b), (d), 0, 0, 0)

__device__ __forceinline__ void lds_barrier() {
    asm volatile("s_waitcnt lgkmcnt(0)\n\ts_barrier" ::: "memory");
}
__device__ __forceinline__ float sigf(float x)   { return 1.f / (1.f + __expf(-x)); }
__device__ __forceinline__ float tanhf_(float x) { return 2.f / (1.f + __expf(-2.f * x)) - 1.f; }
__device__ __forceinline__ f16x4 cvt4h(float4 v) {
    return (f16x4){(_Float16)v.x, (_Float16)v.y, (_Float16)v.z, (_Float16)v.w};
}

// Batched-MFMA LSTM: 2 blocks x 16 batches. Per step per block:
//   G[512x16] = AW[512x160] . bb[160x16],  bb = [h(128); x(16); 1; 0...]
// AW = [W_hh | W_ih | b_ih+b_hh | 0] lives in per-wave A-fragments (registers;
// MFMA operands may be AGPR-allocated - the unified-file path the VALU
// formulation could never unlock). One barrier per step.
// Waves 0-7: gates+cell. Wave 8: FC+segment (global atomics). Wave 9: x/id prefetch.
__global__ __launch_bounds__(640, 1)
void lstm_mfma(
    const float* __restrict__ x,      // [B,T,16]
    const float* __restrict__ W_ih,   // [512,16]
    const float* __restrict__ W_hh,   // [512,128]
    const float* __restrict__ b_ih,   // [512]
    const float* __restrict__ b_hh,   // [512]
    const float* __restrict__ W_fc,   // [3,128]
    float* __restrict__ sums)         // [B,P,3] global, pre-zeroed; atomic accumulate
{
    const int bg   = blockIdx.x;          // batch group: batches bg*16 .. bg*16+15
    const int tid  = threadIdx.x;
    const int lane = tid & 63;
    const int w    = tid >> 6;            // wave id 0..9
    const int q    = lane >> 4;           // quad 0..3
    const int m15  = lane & 15;

    __shared__ __align__(16) _Float16 bb[2][16][BBW];  // [buf][batch n][K=160(+pad)]
    __shared__ int ids_lds[4][16];                     // photo id per step (mod-4 ring)

    // ---- init LDS ----
    {
        _Float16* bf = &bb[0][0][0];
        for (int i = tid; i < 2 * 16 * BBW; i += 640) bf[i] = (_Float16)0.f;
        if (tid < 48) ((int*)ids_lds)[16 + tid] = -1;  // slots 1..3 = -1
    }
    __syncthreads();
    if (tid < 32) bb[tid >> 4][tid & 15][144] = (_Float16)1.f;   // bias column = 1

    // prefetch-wave lane mapping (used by wave 9 and for x_0 staging)
    const int    pn   = lane >> 2;        // batch 0..15
    const int    part = lane & 3;         // 4 floats per part
    const float* xp   = x + ((size_t)(bg * 16 + pn) * T_) * I_ + part * 4;

    if (w == 9) {   // stage x_0 + id_0
        float4 x0 = *(const float4*)(xp);
        *(f16x4*)&bb[0][pn][128 + 4 * part] = cvt4h(x0);
        if (part == 0) ids_lds[0][pn] = (int)x0.z;
    }
    __syncthreads();

    if (w < 8) {
        // =================== gate + cell waves ===================
        const int row = 16 * w + m15;     // gate-relative row (0..127) = A's m index
        // A-fragments: A[m=lane&15][k=quad*8+j]; tile g covers W rows 128g+row.
        #define ALD(g, kk) frag A##g##_##kk; { \
            const float* rp = W_hh + (size_t)(128 * (g) + row) * H_ + 32 * (kk) + 8 * q; \
            A##g##_##kk = (frag){(_Float16)rp[0], (_Float16)rp[1], (_Float16)rp[2], (_Float16)rp[3], \
                                 (_Float16)rp[4], (_Float16)rp[5], (_Float16)rp[6], (_Float16)rp[7]}; }
        #define ALD4(g) frag A##g##_4 = (frag){0, 0, 0, 0, 0, 0, 0, 0}; \
            if (q < 2) { const float* rp = W_ih + (size_t)(128 * (g) + row) * I_ + 8 * q; \
                A##g##_4 = (frag){(_Float16)rp[0], (_Float16)rp[1], (_Float16)rp[2], (_Float16)rp[3], \
                                  (_Float16)rp[4], (_Float16)rp[5], (_Float16)rp[6], (_Float16)rp[7]}; } \
            else if (q == 2) { A##g##_4[0] = (_Float16)(b_ih[128 * (g) + row] + b_hh[128 * (g) + row]); }
        ALD(0,0) ALD(0,1) ALD(0,2) ALD(0,3) ALD4(0)
        ALD(1,0) ALD(1,1) ALD(1,2) ALD(1,3) ALD4(1)
        ALD(2,0) ALD(2,1) ALD(2,2) ALD(2,3) ALD4(2)
        ALD(3,0) ALD(3,1) ALD(3,2) ALD(3,3) ALD4(3)

        float c0 = 0.f, c1 = 0.f, c2 = 0.f, c3 = 0.f;

        #pragma unroll 1
        for (int t = 0; t < T_; ++t) {
            const _Float16* bc = &bb[t & 1][0][0] + (size_t)m15 * BBW + 8 * q;
            frag b0 = *(const frag*)(bc);          // B[k=quad*8+j][n=lane&15]
            frag b1 = *(const frag*)(bc + 32);
            frag b2 = *(const frag*)(bc + 64);
            frag b3 = *(const frag*)(bc + 96);
            frag b4 = *(const frag*)(bc + 128);    // x | bias-1 | zeros

            fragf d0 = {0.f, 0.f, 0.f, 0.f};
            fragf d1 = {0.f, 0.f, 0.f, 0.f};
            fragf d2 = {0.f, 0.f, 0.f, 0.f};
            fragf d3 = {0.f, 0.f, 0.f, 0.f};
            MFMA16(d0, A0_0, b0); MFMA16(d1, A1_0, b0); MFMA16(d2, A2_0, b0); MFMA16(d3, A3_0, b0);
            MFMA16(d0, A0_1, b1); MFMA16(d1, A1_1, b1); MFMA16(d2, A2_1, b1); MFMA16(d3, A3_1, b1);
            MFMA16(d0, A0_2, b2); MFMA16(d1, A1_2, b2); MFMA16(d2, A2_2, b2); MFMA16(d3, A3_2, b2);
            MFMA16(d0, A0_3, b3); MFMA16(d1, A1_3, b3); MFMA16(d2, A2_3, b3); MFMA16(d3, A3_3, b3);
            MFMA16(d0, A0_4, b4); MFMA16(d1, A1_4, b4); MFMA16(d2, A2_4, b4); MFMA16(d3, A3_4, b4);

            // D layout: col(batch)=lane&15, row=quad*4+reg -> unit j=16w+4q+r
            float h0, h1, h2, h3;
            #define CELL(r) { \
                const float gi = sigf(d0[r]); const float gf = sigf(d1[r]); \
                const float gg = tanhf_(d2[r]); const float go = sigf(d3[r]); \
                c##r = fmaf(gf, c##r, gi * gg); h##r = go * tanhf_(c##r); }
            CELL(0) CELL(1) CELL(2) CELL(3)
            #undef CELL

            *(f16x4*)(&bb[(t + 1) & 1][m15][16 * w + 4 * q]) =
                (f16x4){(_Float16)h0, (_Float16)h1, (_Float16)h2, (_Float16)h3};

            lds_barrier();
        }
    } else if (w == 8) {
        // =================== FC + segment wave ===================
        // A = W_fc padded to 16 rows (rows 3..15 zero)
        #define FLD(kk) frag F##kk = (frag){0, 0, 0, 0, 0, 0, 0, 0}; \
            if (m15 < O_) { const float* rp = W_fc + (size_t)m15 * H_ + 32 * (kk) + 8 * q; \
                F##kk = (frag){(_Float16)rp[0], (_Float16)rp[1], (_Float16)rp[2], (_Float16)rp[3], \
                               (_Float16)rp[4], (_Float16)rp[5], (_Float16)rp[6], (_Float16)rp[7]}; }
        FLD(0) FLD(1) FLD(2) FLD(3)

        float* const sums_g = sums + (size_t)(bg * 16) * P_ * O_;

        #pragma unroll 1
        for (int t = 0; t < T_; ++t) {
            // FC on h_{t-1} (bb[t&1]) paired with id_{t-1} (ring slot (t-1)&3)
            const _Float16* bc = &bb[t & 1][0][0] + (size_t)m15 * BBW + 8 * q;
            frag b0 = *(const frag*)(bc);
            frag b1 = *(const frag*)(bc + 32);
            frag b2 = *(const frag*)(bc + 64);
            frag b3 = *(const frag*)(bc + 96);
            fragf d = {0.f, 0.f, 0.f, 0.f};
            MFMA16(d, F0, b0); MFMA16(d, F1, b1); MFMA16(d, F2, b2); MFMA16(d, F3, b3);

            const int idn = ids_lds[(t - 1) & 3][m15];
            if (lane < 16 && (unsigned)idn < P_) {     // lane<16 => quad 0 => rows 0..2
                float* sp = sums_g + ((size_t)m15 * P_ + idn) * O_;
                atomicAdd(sp + 0, d[0]);
                atomicAdd(sp + 1, d[1]);
                atomicAdd(sp + 2, d[2]);
            }
            lds_barrier();
        }
        {   // tail: h_{T-1} with id_{T-1}
            const _Float16* bc = &bb[T_ & 1][0][0] + (size_t)m15 * BBW + 8 * q;
            frag b0 = *(const frag*)(bc);
            frag b1 = *(const frag*)(bc + 32);
            frag b2 = *(const frag*)(bc + 64);
            frag b3 = *(const frag*)(bc + 96);
            fragf d = {0.f, 0.f, 0.f, 0.f};
            MFMA16(d, F0, b0); MFMA16(d, F1, b1); MFMA16(d, F2, b2); MFMA16(d, F3, b3);
            const int idn = ids_lds[(T_ - 1) & 3][m15];
            if (lane < 16 && (unsigned)idn < P_) {
                float* sp = sums_g + ((size_t)m15 * P_ + idn) * O_;
                atomicAdd(sp + 0, d[0]);
                atomicAdd(sp + 1, d[1]);
                atomicAdd(sp + 2, d[2]);
            }
        }
    } else {
        // =================== x/id prefetch wave (w == 9) ===================
        float4 xr = make_float4(0.f, 0.f, 0.f, 0.f);   // holds x_{t+1}
        if (T_ > 1) xr = *(const float4*)(xp + (size_t)1 * I_);

        #pragma unroll 1
        for (int t = 0; t < T_; ++t) {
            float4 xn = xr;                            // next: x_{t+2}
            if (t + 2 < T_) xn = *(const float4*)(xp + (size_t)(t + 2) * I_);
            if (t + 1 < T_) {
                *(f16x4*)&bb[(t + 1) & 1][pn][128 + 4 * part] = cvt4h(xr);
                if (part == 0) ids_lds[(t + 1) & 3][pn] = (int)xr.z;
            }
            xr = xn;
            lds_barrier();
        }
    }
}

// per-(b,p) occurrence counts — parallel, off the serial loop (verified R8)
__global__ void count_kernel(const float* __restrict__ x,
                             float* __restrict__ counts)
{
    const int b = blockIdx.x;
    __shared__ int cnt[P_];
    for (int i = threadIdx.x; i < P_; i += 256) cnt[i] = 0;
    __syncthreads();
    const float* xb = x + (size_t)b * T_ * I_;
    for (int t = threadIdx.x; t < T_; t += 256) {
        const int id = (int)xb[t * I_ + 2];
        if ((unsigned)id < P_) atomicAdd(&cnt[id], 1);
    }
    __syncthreads();
    for (int i = threadIdx.x; i < P_; i += 256)
        counts[b * P_ + i] = (float)cnt[i];
}

// out[b,p,o] = (sums[b,p,o] + cnt*b_fc[o]) / max(cnt,1)
__global__ void finalize_kernel(const float* __restrict__ sums,
                                const float* __restrict__ counts,
                                const float* __restrict__ b_fc,
                                float* __restrict__ out)
{
    const int idx = blockIdx.x * blockDim.x + threadIdx.x;
    if (idx >= B_ * P_ * O_) return;
    const int o  = idx % O_;
    const int bp = idx / O_;
    const float cnt = counts[bp];
    const float denom = (cnt > 0.f) ? cnt : 1.f;
    out[idx] = (sums[idx] + cnt * b_fc[o]) / denom;
}

extern "C" void kernel_launch(void* const* d_in, const int* in_sizes, int n_in,
                              void* d_out, int out_size, void* d_ws, size_t ws_size,
                              hipStream_t stream) {
    const float* x    = (const float*)d_in[0];
    const float* W_ih = (const float*)d_in[1];
    const float* W_hh = (const float*)d_in[2];
    const float* b_ih = (const float*)d_in[3];
    const float* b_hh = (const float*)d_in[4];
    const float* W_fc = (const float*)d_in[5];
    const float* b_fc = (const float*)d_in[6];
    // d_in[7] = num_photos (==P_, fixed by the problem)

    float* out    = (float*)d_out;
    float* sums   = (float*)d_ws;                 // B*P*3 floats (atomic-accumulated)
    float* counts = sums + (size_t)B_ * P_ * O_;  // B*P floats (overwritten)

    hipMemsetAsync(sums, 0, (size_t)B_ * P_ * O_ * sizeof(float), stream);

    count_kernel<<<B_, 256, 0, stream>>>(x, counts);
    lstm_mfma<<<2, 640, 0, stream>>>(x, W_ih, W_hh, b_ih, b_hh, W_fc, sums);

    const int n = B_ * P_ * O_;
    finalize_kernel<<<(n + 255) / 256, 256, 0, stream>>>(sums, counts, b_fc, out);
}